// Round 7
// baseline (135.757 us; speedup 1.0000x reference)
//
#include <hip/hip_runtime.h>
#include <hip/hip_bf16.h>

#define B 512
#define N 1024
#define D 1024
#define FUSE 1024
#define A 256

typedef float f32x4 __attribute__((ext_vector_type(4)));
typedef short bf16x8 __attribute__((ext_vector_type(8)));
typedef unsigned short u16x4 __attribute__((ext_vector_type(4)));

__device__ __forceinline__ float fast_exp2(float x) { return __builtin_amdgcn_exp2f(x); }
__device__ __forceinline__ float fast_rcp(float x)  { return __builtin_amdgcn_rcpf(x); }

static constexpr float TANH_C = 2.8853900817779268f; // 2*log2(e)
static constexpr float LOG2E  = 1.4426950408889634f;

__device__ __forceinline__ unsigned short f2bf(float x) {
    __hip_bfloat16 h = __float2bfloat16(x);
    return *reinterpret_cast<unsigned short*>(&h);
}

// ---------------------------------------------------------------------------
// Kernel 0: cast inputs to bf16. Straight: fuse_rep, conf. Transposed (so the
// GEMM B-operand is K-contiguous): conf^T, (Wq*TANH_C)^T, (Wk*TANH_C)^T.
// ---------------------------------------------------------------------------
__global__ __launch_bounds__(256) void cast_kernel(
    const float* __restrict__ fuse, const float* __restrict__ conf,
    const float* __restrict__ Wq, const float* __restrict__ Wk,
    short* __restrict__ fuse_bf, short* __restrict__ conf_bf,
    short* __restrict__ confT, short* __restrict__ WqT, short* __restrict__ WkT)
{
    __shared__ float tile[64 * 65];
    int bid = blockIdx.x;
    const float* src; short* dstS = nullptr; short* dstT = nullptr;
    int r0, c0, spitch; float scale = 1.0f;
    if (bid < 128) {
        src = fuse; dstS = fuse_bf; spitch = FUSE;
        r0 = (bid >> 4) * 64; c0 = (bid & 15) * 64;
    } else if (bid < 384) {
        int b = bid - 128; src = conf; dstS = conf_bf; dstT = confT; spitch = D;
        r0 = (b >> 4) * 64; c0 = (b & 15) * 64;
    } else if (bid < 448) {
        int b = bid - 384; src = Wq; dstT = WqT; spitch = A; scale = TANH_C;
        r0 = (b >> 2) * 64; c0 = (b & 3) * 64;
    } else {
        int b = bid - 448; src = Wk; dstT = WkT; spitch = A; scale = TANH_C;
        r0 = (b >> 2) * 64; c0 = (b & 3) * 64;
    }
    const int tr = threadIdx.x >> 4, tc = (threadIdx.x & 15) * 4;

    f32x4 v[4];
#pragma unroll
    for (int i = 0; i < 4; ++i) {
        v[i] = *(const f32x4*)(src + (size_t)(r0 + tr + 16 * i) * spitch + c0 + tc);
#pragma unroll
        for (int j = 0; j < 4; ++j) v[i][j] *= scale;
    }
    if (dstS) {
#pragma unroll
        for (int i = 0; i < 4; ++i) {
            u16x4 o;
#pragma unroll
            for (int j = 0; j < 4; ++j) o[j] = f2bf(v[i][j]);
            *(u16x4*)(dstS + (size_t)(r0 + tr + 16 * i) * spitch + c0 + tc) = o;
        }
    }
    if (dstT) {
#pragma unroll
        for (int i = 0; i < 4; ++i)
#pragma unroll
            for (int j = 0; j < 4; ++j) tile[(tr + 16 * i) * 65 + tc + j] = v[i][j];
        __syncthreads();
#pragma unroll
        for (int i = 0; i < 4; ++i) {
            int orow = tr + 16 * i;
            u16x4 o;
#pragma unroll
            for (int j = 0; j < 4; ++j) o[j] = f2bf(tile[(tc + j) * 65 + orow]);
            *(u16x4*)(dstT + (size_t)(c0 + orow) * 1024 + r0 + tc) = o;
        }
    }
}

// ---------------------------------------------------------------------------
// 32x64-tile bf16 MFMA GEMM, 2-phase double-buffered global_load_lds pipeline
// (proven structure from round-6 fin kernel). lda = 1024 for all our operands.
// LDS [rows][128 B] XOR-swizzled via pre-swizzled SOURCE address (rule #21).
// ---------------------------------------------------------------------------
__device__ __forceinline__ void gemm32x64_pipe(
    const short* __restrict__ Ag, const short* __restrict__ Btg,
    float* __restrict__ C, int ldc, int m0, int n0,
    char* As, char* Bs)   // As: 2 x 4 KB, Bs: 2 x 8 KB
{
    const int tid = threadIdx.x;
    const int w = tid >> 6, l = tid & 63;
    const int wm = w >> 1, wn = w & 1;
    const int lr = l & 15;
    const int cr = (l >> 4) * 4;
    const int rsub = l >> 3;
    const int ssrc = ((l & 7) ^ rsub) << 3;

    auto stage = [&](int buf, int k0) {
        {   // A: 4 chunks (32 rows), one per wave
            int row = (w << 3) | rsub;
            __builtin_amdgcn_global_load_lds(
                (const __attribute__((address_space(1))) unsigned int*)
                    (Ag + (size_t)(m0 + row) * 1024 + k0 + ssrc),
                (__attribute__((address_space(3))) unsigned int*)(As + (buf << 12) + (w << 10)),
                16, 0, 0);
        }
#pragma unroll
        for (int p = 0; p < 2; ++p) {   // B: 8 chunks (64 rows), two per wave
            int chunk = (w << 1) | p;
            int row = (chunk << 3) | rsub;
            __builtin_amdgcn_global_load_lds(
                (const __attribute__((address_space(1))) unsigned int*)
                    (Btg + (size_t)(n0 + row) * 1024 + k0 + ssrc),
                (__attribute__((address_space(3))) unsigned int*)(Bs + (buf << 13) + (chunk << 10)),
                16, 0, 0);
        }
    };

    f32x4 acc[2] = {};
    stage(0, 0);
    asm volatile("s_waitcnt vmcnt(0)" ::: "memory");
    __builtin_amdgcn_s_barrier();

    int cur = 0;
    for (int t = 0; t < 16; ++t) {
        if (t < 15) stage(cur ^ 1, (t + 1) << 6);

        const char* Ab = As + (cur << 12);
        const char* Bb = Bs + (cur << 13);
#pragma unroll
        for (int ks = 0; ks < 2; ++ks) {
            int j = ks * 64 + ((l >> 4) << 4);
            int r = wm * 16 + lr;
            bf16x8 af = *(const bf16x8*)(Ab + r * 128 + (j ^ ((r & 7) << 4)));
#pragma unroll
            for (int i = 0; i < 2; ++i) {
                int c = wn * 32 + i * 16 + lr;
                bf16x8 bq = *(const bf16x8*)(Bb + c * 128 + (j ^ ((c & 7) << 4)));
                acc[i] = __builtin_amdgcn_mfma_f32_16x16x32_bf16(af, bq, acc[i], 0, 0, 0);
            }
        }
        asm volatile("s_waitcnt vmcnt(0)" ::: "memory");
        __builtin_amdgcn_s_barrier();
        cur ^= 1;
    }

#pragma unroll
    for (int i = 0; i < 2; ++i) {
        float* cp = C + (size_t)(m0 + wm * 16 + cr) * ldc + n0 + wn * 32 + i * 16 + lr;
#pragma unroll
        for (int r = 0; r < 4; ++r) cp[(size_t)r * ldc] = acc[i][r];
    }
}

// Kernel 1: q' = fuse_bf @ WqT^T, k' = conf_bf @ WkT^T. Full K, 192 blocks.
__global__ __launch_bounds__(256) void qk_gemm_kernel(
    const short* __restrict__ fuse_bf, const short* __restrict__ conf_bf,
    const short* __restrict__ WqT, const short* __restrict__ WkT,
    float* __restrict__ qbuf, float* __restrict__ kbuf)
{
    __shared__ char As[8192];
    __shared__ char Bs[16384];
    int bid = blockIdx.x;
    if (bid < 64) {   // q: 16 m-tiles x 4 n-tiles
        gemm32x64_pipe(fuse_bf, WqT, qbuf, A, (bid >> 2) * 32, (bid & 3) * 64, As, Bs);
    } else {          // k: 32 m-tiles x 4 n-tiles
        bid -= 64;
        gemm32x64_pipe(conf_bf, WkT, kbuf, A, (bid >> 2) * 32, (bid & 3) * 64, As, Bs);
    }
}

// Kernel 4: fin = w_bf @ confT^T. 256 blocks.
__global__ __launch_bounds__(256) void fin_gemm_kernel(
    const short* __restrict__ wb, const short* __restrict__ confT,
    float* __restrict__ out)
{
    __shared__ char As[8192];
    __shared__ char Bs[16384];
    gemm32x64_pipe(wb, confT, out, D, blockIdx.y * 32, blockIdx.x * 64, As, Bs);
}

// ---------------------------------------------------------------------------
// Kernel 2: scores. 32(b) x 64(n) tile per block, A in 2 chunks of 128.
// Each thread: 4 b-rows x 2 n-cols = 8 accs -> 6 LDS reads per 32 evals.
// ---------------------------------------------------------------------------
__global__ __launch_bounds__(256) void scores_kernel(
    const float* __restrict__ qbuf, const float* __restrict__ kbuf,
    const float* __restrict__ wt, float* __restrict__ sbuf)
{
    __shared__ f32x4 qs[32 * 32];   // 16 KB
    __shared__ f32x4 ks[64 * 32];   // 32 KB
    const int tid = threadIdx.x;
    const int bid = blockIdx.x;
    const int b0 = (bid & 15) * 32;
    const int n0 = (bid >> 4) * 64;

    const f32x4* q4 = (const f32x4*)qbuf;   // [512][64]
    const f32x4* k4 = (const f32x4*)kbuf;   // [1024][64]
    const f32x4* wt4 = (const f32x4*)wt;
    const int bl = tid >> 5;    // 0..7
    const int nl = tid & 31;    // 0..31

    float a00 = 0.f, a10 = 0.f, a20 = 0.f, a30 = 0.f;
    float a01 = 0.f, a11 = 0.f, a21 = 0.f, a31 = 0.f;
#pragma unroll
    for (int c = 0; c < 2; ++c) {
#pragma unroll
        for (int j = 0; j < 4; ++j) {       // qs: 1024 f32x4
            int idx = tid + j * 256;
            int r = idx >> 5, col = idx & 31;
            qs[r * 32 + col] = q4[(size_t)(b0 + r) * 64 + c * 32 + col];
        }
#pragma unroll
        for (int j = 0; j < 8; ++j) {       // ks: 2048 f32x4, XOR-swizzled
            int idx = tid + j * 256;
            int r = idx >> 5, col = idx & 31;
            ks[r * 32 + (col ^ (r & 15))] = k4[(size_t)(n0 + r) * 64 + c * 32 + col];
        }
        __syncthreads();
        for (int a4 = 0; a4 < 32; ++a4) {
            int kx = a4 ^ (nl & 15);
            f32x4 kv0 = ks[nl * 32 + kx];
            f32x4 kv1 = ks[(nl + 32) * 32 + kx];
            f32x4 wv = wt4[c * 32 + a4];
            f32x4 q0 = qs[(bl) * 32 + a4];
            f32x4 q1 = qs[(bl + 8) * 32 + a4];
            f32x4 q2 = qs[(bl + 16) * 32 + a4];
            f32x4 q3 = qs[(bl + 24) * 32 + a4];
#pragma unroll
            for (int cc = 0; cc < 4; ++cc) {
                float k0 = kv0[cc], k1 = kv1[cc], wc = wv[cc];
                a00 += wc * fast_rcp(fast_exp2(q0[cc] + k0) + 1.0f);
                a10 += wc * fast_rcp(fast_exp2(q1[cc] + k0) + 1.0f);
                a20 += wc * fast_rcp(fast_exp2(q2[cc] + k0) + 1.0f);
                a30 += wc * fast_rcp(fast_exp2(q3[cc] + k0) + 1.0f);
                a01 += wc * fast_rcp(fast_exp2(q0[cc] + k1) + 1.0f);
                a11 += wc * fast_rcp(fast_exp2(q1[cc] + k1) + 1.0f);
                a21 += wc * fast_rcp(fast_exp2(q2[cc] + k1) + 1.0f);
                a31 += wc * fast_rcp(fast_exp2(q3[cc] + k1) + 1.0f);
            }
        }
        __syncthreads();
    }
    sbuf[(size_t)(b0 + bl) * N + n0 + nl]           = -2.0f * a00;
    sbuf[(size_t)(b0 + bl + 8) * N + n0 + nl]       = -2.0f * a10;
    sbuf[(size_t)(b0 + bl + 16) * N + n0 + nl]      = -2.0f * a20;
    sbuf[(size_t)(b0 + bl + 24) * N + n0 + nl]      = -2.0f * a30;
    sbuf[(size_t)(b0 + bl) * N + n0 + 32 + nl]      = -2.0f * a01;
    sbuf[(size_t)(b0 + bl + 8) * N + n0 + 32 + nl]  = -2.0f * a11;
    sbuf[(size_t)(b0 + bl + 16) * N + n0 + 32 + nl] = -2.0f * a21;
    sbuf[(size_t)(b0 + bl + 24) * N + n0 + 32 + nl] = -2.0f * a31;
}

// ---------------------------------------------------------------------------
// Kernel 3: row softmax (no max-pass: |s| <= 2*sum|wt| ~ 26, f32-safe),
// times probs[n]; emit bf16 attn weights.
// ---------------------------------------------------------------------------
__global__ __launch_bounds__(256) void softmax_kernel(
    const float* __restrict__ s, const float* __restrict__ probs,
    short* __restrict__ wbuf)
{
    const int b = blockIdx.x, tid = threadIdx.x;
    const f32x4* s4 = (const f32x4*)(s + (size_t)b * N);
    f32x4 v = s4[tid];

    f32x4 e;
#pragma unroll
    for (int c = 0; c < 4; ++c) e[c] = fast_exp2(v[c] * LOG2E);
    float sum = e[0] + e[1] + e[2] + e[3];
    for (int off = 32; off > 0; off >>= 1) sum += __shfl_xor(sum, off);
    __shared__ float reds[4];
    const int wid = tid >> 6, lane = tid & 63;
    if (lane == 0) reds[wid] = sum;
    __syncthreads();
    sum = reds[0] + reds[1] + reds[2] + reds[3];

    const float inv = fast_rcp(sum);
    const f32x4* p4 = (const f32x4*)probs;
    f32x4 p = p4[tid];
    u16x4 o;
#pragma unroll
    for (int c = 0; c < 4; ++c) o[c] = f2bf(e[c] * inv * p[c]);
    ((u16x4*)(wbuf + (size_t)b * N))[tid] = o;
}

// ---------------------------------------------------------------------------
extern "C" void kernel_launch(void* const* d_in, const int* in_sizes, int n_in,
                              void* d_out, int out_size, void* d_ws, size_t ws_size,
                              hipStream_t stream) {
    const float* conf     = (const float*)d_in[0]; // [N,D]
    const float* fuse_rep = (const float*)d_in[1]; // [B,FUSE]
    const float* probs    = (const float*)d_in[2]; // [1,N]
    const float* Wq       = (const float*)d_in[3]; // [FUSE,A]
    const float* Wk       = (const float*)d_in[4]; // [D,A]
    const float* wt       = (const float*)d_in[5]; // [A]
    float* out = (float*)d_out;                    // [B,D]

    char* w = (char*)d_ws;
    float* qbuf   = (float*)(w);                    // 512 KB  @ 0
    float* kbuf   = (float*)(w + (1u << 20));       //   1 MB  @ 1M
    float* sbuf   = (float*)(w + (3u << 20));       //   2 MB  @ 3M
    short* fuse_bf= (short*)(w + (5u << 20));       //   1 MB  @ 5M
    short* conf_bf= (short*)(w + (6u << 20));       //   2 MB  @ 6M
    short* confT  = (short*)(w + (8u << 20));       //   2 MB  @ 8M
    short* WqT    = (short*)(w + (10u << 20));      // 512 KB  @ 10M
    short* WkT    = (short*)(w + (10u << 20) + (512u << 10)); // 512 KB
    short* wbuf   = (short*)(w);                    //   1 MB, aliases q/k (free after scores)

    hipLaunchKernelGGL(cast_kernel, dim3(512), dim3(256), 0, stream,
                       fuse_rep, conf, Wq, Wk, fuse_bf, conf_bf, confT, WqT, WkT);
    hipLaunchKernelGGL(qk_gemm_kernel, dim3(192), dim3(256), 0, stream,
                       fuse_bf, conf_bf, WqT, WkT, qbuf, kbuf);
    hipLaunchKernelGGL(scores_kernel, dim3(256), dim3(256), 0, stream,
                       qbuf, kbuf, wt, sbuf);
    hipLaunchKernelGGL(softmax_kernel, dim3(B), dim3(256), 0, stream,
                       sbuf, probs, wbuf);
    hipLaunchKernelGGL(fin_gemm_kernel, dim3(D / 64, B / 32), dim3(256), 0, stream,
                       wbuf, confT, out);
}

// Round 8
// 133.650 us; speedup vs baseline: 1.0158x; 1.0158x over previous
//
#include <hip/hip_runtime.h>
#include <hip/hip_bf16.h>

#define B 512
#define N 1024
#define D 1024
#define FUSE 1024
#define A 256

typedef float f32x4 __attribute__((ext_vector_type(4)));
typedef short bf16x8 __attribute__((ext_vector_type(8)));
typedef unsigned short u16x4 __attribute__((ext_vector_type(4)));

__device__ __forceinline__ float fast_exp2(float x) { return __builtin_amdgcn_exp2f(x); }
__device__ __forceinline__ float fast_rcp(float x)  { return __builtin_amdgcn_rcpf(x); }

static constexpr float TANH_C     = 2.8853900817779268f;  // 2*log2(e)
static constexpr float NEG2LOG2E  = -2.8853900817779268f; // -2*log2(e)

__device__ __forceinline__ unsigned short f2bf(float x) {
    __hip_bfloat16 h = __float2bfloat16(x);
    return *reinterpret_cast<unsigned short*>(&h);
}

// ---------------------------------------------------------------------------
// Kernel 0: cast inputs to bf16 (straight: fuse, conf; transposed: conf^T,
// (Wq*TANH_C)^T, (Wk*TANH_C)^T). Block 0 also zeroes rowsum[512].
// ---------------------------------------------------------------------------
__global__ __launch_bounds__(256) void cast_kernel(
    const float* __restrict__ fuse, const float* __restrict__ conf,
    const float* __restrict__ Wq, const float* __restrict__ Wk,
    short* __restrict__ fuse_bf, short* __restrict__ conf_bf,
    short* __restrict__ confT, short* __restrict__ WqT, short* __restrict__ WkT,
    float* __restrict__ rowsum)
{
    __shared__ float tile[64 * 65];
    int bid = blockIdx.x;
    if (bid == 0 && threadIdx.x < 128)
        ((f32x4*)rowsum)[threadIdx.x] = f32x4{0.f, 0.f, 0.f, 0.f};

    const float* src; short* dstS = nullptr; short* dstT = nullptr;
    int r0, c0, spitch; float scale = 1.0f;
    if (bid < 128) {
        src = fuse; dstS = fuse_bf; spitch = FUSE;
        r0 = (bid >> 4) * 64; c0 = (bid & 15) * 64;
    } else if (bid < 384) {
        int b = bid - 128; src = conf; dstS = conf_bf; dstT = confT; spitch = D;
        r0 = (b >> 4) * 64; c0 = (b & 15) * 64;
    } else if (bid < 448) {
        int b = bid - 384; src = Wq; dstT = WqT; spitch = A; scale = TANH_C;
        r0 = (b >> 2) * 64; c0 = (b & 3) * 64;
    } else {
        int b = bid - 448; src = Wk; dstT = WkT; spitch = A; scale = TANH_C;
        r0 = (b >> 2) * 64; c0 = (b & 3) * 64;
    }
    const int tr = threadIdx.x >> 4, tc = (threadIdx.x & 15) * 4;

    f32x4 v[4];
#pragma unroll
    for (int i = 0; i < 4; ++i) {
        v[i] = *(const f32x4*)(src + (size_t)(r0 + tr + 16 * i) * spitch + c0 + tc);
#pragma unroll
        for (int j = 0; j < 4; ++j) v[i][j] *= scale;
    }
    if (dstS) {
#pragma unroll
        for (int i = 0; i < 4; ++i) {
            u16x4 o;
#pragma unroll
            for (int j = 0; j < 4; ++j) o[j] = f2bf(v[i][j]);
            *(u16x4*)(dstS + (size_t)(r0 + tr + 16 * i) * spitch + c0 + tc) = o;
        }
    }
    if (dstT) {
#pragma unroll
        for (int i = 0; i < 4; ++i)
#pragma unroll
            for (int j = 0; j < 4; ++j) tile[(tr + 16 * i) * 65 + tc + j] = v[i][j];
        __syncthreads();
#pragma unroll
        for (int i = 0; i < 4; ++i) {
            int orow = tr + 16 * i;
            u16x4 o;
#pragma unroll
            for (int j = 0; j < 4; ++j) o[j] = f2bf(tile[(tc + j) * 65 + orow]);
            *(u16x4*)(dstT + (size_t)(c0 + orow) * 1024 + r0 + tc) = o;
        }
    }
}

// ---------------------------------------------------------------------------
// 32x64-tile bf16 MFMA GEMM, 2-phase double-buffered global_load_lds pipeline.
// lda = 1024 for all operands. LDS [rows][128 B] XOR-swizzled via pre-swizzled
// SOURCE address (rule #21). Optional row-scale epilogue (for fin normalize).
// ---------------------------------------------------------------------------
template <bool SCALE_ROWS>
__device__ __forceinline__ void gemm32x64_pipe(
    const short* __restrict__ Ag, const short* __restrict__ Btg,
    float* __restrict__ C, int ldc, int m0, int n0,
    const float* __restrict__ rowsum,
    char* As, char* Bs)   // As: 2 x 4 KB, Bs: 2 x 8 KB
{
    const int tid = threadIdx.x;
    const int w = tid >> 6, l = tid & 63;
    const int wm = w >> 1, wn = w & 1;
    const int lr = l & 15;
    const int cr = (l >> 4) * 4;
    const int rsub = l >> 3;
    const int ssrc = ((l & 7) ^ rsub) << 3;

    auto stage = [&](int buf, int k0) {
        {   // A: 4 chunks (32 rows), one per wave
            int row = (w << 3) | rsub;
            __builtin_amdgcn_global_load_lds(
                (const __attribute__((address_space(1))) unsigned int*)
                    (Ag + (size_t)(m0 + row) * 1024 + k0 + ssrc),
                (__attribute__((address_space(3))) unsigned int*)(As + (buf << 12) + (w << 10)),
                16, 0, 0);
        }
#pragma unroll
        for (int p = 0; p < 2; ++p) {   // B: 8 chunks (64 rows), two per wave
            int chunk = (w << 1) | p;
            int row = (chunk << 3) | rsub;
            __builtin_amdgcn_global_load_lds(
                (const __attribute__((address_space(1))) unsigned int*)
                    (Btg + (size_t)(n0 + row) * 1024 + k0 + ssrc),
                (__attribute__((address_space(3))) unsigned int*)(Bs + (buf << 13) + (chunk << 10)),
                16, 0, 0);
        }
    };

    f32x4 acc[2] = {};
    stage(0, 0);
    asm volatile("s_waitcnt vmcnt(0)" ::: "memory");
    __builtin_amdgcn_s_barrier();

    int cur = 0;
    for (int t = 0; t < 16; ++t) {
        if (t < 15) stage(cur ^ 1, (t + 1) << 6);

        const char* Ab = As + (cur << 12);
        const char* Bb = Bs + (cur << 13);
#pragma unroll
        for (int ks = 0; ks < 2; ++ks) {
            int j = ks * 64 + ((l >> 4) << 4);
            int r = wm * 16 + lr;
            bf16x8 af = *(const bf16x8*)(Ab + r * 128 + (j ^ ((r & 7) << 4)));
#pragma unroll
            for (int i = 0; i < 2; ++i) {
                int c = wn * 32 + i * 16 + lr;
                bf16x8 bq = *(const bf16x8*)(Bb + c * 128 + (j ^ ((c & 7) << 4)));
                acc[i] = __builtin_amdgcn_mfma_f32_16x16x32_bf16(af, bq, acc[i], 0, 0, 0);
            }
        }
        asm volatile("s_waitcnt vmcnt(0)" ::: "memory");
        __builtin_amdgcn_s_barrier();
        cur ^= 1;
    }

    f32x4 inv = {1.f, 1.f, 1.f, 1.f};
    if (SCALE_ROWS) {
        const f32x4 rs = *(const f32x4*)(rowsum + m0 + wm * 16 + cr);
#pragma unroll
        for (int r = 0; r < 4; ++r) inv[r] = fast_rcp(rs[r]);
    }
#pragma unroll
    for (int i = 0; i < 2; ++i) {
        float* cp = C + (size_t)(m0 + wm * 16 + cr) * ldc + n0 + wn * 32 + i * 16 + lr;
#pragma unroll
        for (int r = 0; r < 4; ++r) cp[(size_t)r * ldc] = acc[i][r] * inv[r];
    }
}

// Kernel 1: q' = fuse_bf @ WqT^T, k' = conf_bf @ WkT^T. Full K, 192 blocks.
__global__ __launch_bounds__(256) void qk_gemm_kernel(
    const short* __restrict__ fuse_bf, const short* __restrict__ conf_bf,
    const short* __restrict__ WqT, const short* __restrict__ WkT,
    float* __restrict__ qbuf, float* __restrict__ kbuf)
{
    __shared__ char As[8192];
    __shared__ char Bs[16384];
    int bid = blockIdx.x;
    if (bid < 64) {
        gemm32x64_pipe<false>(fuse_bf, WqT, qbuf, A, (bid >> 2) * 32, (bid & 3) * 64,
                              nullptr, As, Bs);
    } else {
        bid -= 64;
        gemm32x64_pipe<false>(conf_bf, WkT, kbuf, A, (bid >> 2) * 32, (bid & 3) * 64,
                              nullptr, As, Bs);
    }
}

// Kernel 3: fin = (wbuf @ confT^T) / rowsum[row]. 256 blocks.
__global__ __launch_bounds__(256) void fin_gemm_kernel(
    const short* __restrict__ wb, const short* __restrict__ confT,
    const float* __restrict__ rowsum, float* __restrict__ out)
{
    __shared__ char As[8192];
    __shared__ char Bs[16384];
    gemm32x64_pipe<true>(wb, confT, out, D, blockIdx.y * 32, blockIdx.x * 64,
                         rowsum, As, Bs);
}

// ---------------------------------------------------------------------------
// Kernel 2: scores + unnormalized softmax. 32(b) x 32(n) tile, A in 2 chunks
// (32 KB LDS -> 5 blocks/CU). Emits wbuf[b,n] = bf16(e*p[n]) where
// e = exp2(-2*log2e * acc) = exp(score), and atomically accumulates
// rowsum[b] += sum_n e (shfl-reduced, 32 atomics/block).
// ---------------------------------------------------------------------------
__global__ __launch_bounds__(256) void scores_kernel(
    const float* __restrict__ qbuf, const float* __restrict__ kbuf,
    const float* __restrict__ wt, const float* __restrict__ probs,
    short* __restrict__ wbuf, float* __restrict__ rowsum)
{
    __shared__ f32x4 qs[32 * 32];   // 16 KB
    __shared__ f32x4 ks[32 * 32];   // 16 KB
    const int tid = threadIdx.x;
    const int bid = blockIdx.x;
    const int b0 = (bid & 15) * 32;
    const int n0 = (bid >> 4) * 32;

    const f32x4* q4 = (const f32x4*)qbuf;   // [512][64]
    const f32x4* k4 = (const f32x4*)kbuf;   // [1024][64]
    const f32x4* wt4 = (const f32x4*)wt;
    const int bl = tid >> 5;    // 0..7
    const int nl = tid & 31;    // 0..31

    float acc0 = 0.f, acc1 = 0.f, acc2 = 0.f, acc3 = 0.f;
#pragma unroll
    for (int c = 0; c < 2; ++c) {
#pragma unroll
        for (int j = 0; j < 4; ++j) {
            int idx = tid + j * 256;
            int r = idx >> 5, col = idx & 31;
            qs[r * 32 + col] = q4[(size_t)(b0 + r) * 64 + c * 32 + col];
            ks[r * 32 + (col ^ (r & 15))] = k4[(size_t)(n0 + r) * 64 + c * 32 + col];
        }
        __syncthreads();
        for (int a4 = 0; a4 < 32; ++a4) {
            f32x4 kv = ks[nl * 32 + (a4 ^ (nl & 15))];
            f32x4 wv = wt4[c * 32 + a4];
            f32x4 q0 = qs[(bl) * 32 + a4];
            f32x4 q1 = qs[(bl + 8) * 32 + a4];
            f32x4 q2 = qs[(bl + 16) * 32 + a4];
            f32x4 q3 = qs[(bl + 24) * 32 + a4];
#pragma unroll
            for (int cc = 0; cc < 4; ++cc) {
                float kc = kv[cc], wc = wv[cc];
                acc0 += wc * fast_rcp(fast_exp2(q0[cc] + kc) + 1.0f);
                acc1 += wc * fast_rcp(fast_exp2(q1[cc] + kc) + 1.0f);
                acc2 += wc * fast_rcp(fast_exp2(q2[cc] + kc) + 1.0f);
                acc3 += wc * fast_rcp(fast_exp2(q3[cc] + kc) + 1.0f);
            }
        }
        __syncthreads();
    }

    // e = exp(score) = exp2(NEG2LOG2E * acc)  (no max-pass: |score| <= ~26)
    const float e0 = fast_exp2(acc0 * NEG2LOG2E);
    const float e1 = fast_exp2(acc1 * NEG2LOG2E);
    const float e2 = fast_exp2(acc2 * NEG2LOG2E);
    const float e3 = fast_exp2(acc3 * NEG2LOG2E);

    const float pcol = probs[n0 + nl];
    wbuf[(size_t)(b0 + bl) * N + n0 + nl]      = (short)f2bf(e0 * pcol);
    wbuf[(size_t)(b0 + bl + 8) * N + n0 + nl]  = (short)f2bf(e1 * pcol);
    wbuf[(size_t)(b0 + bl + 16) * N + n0 + nl] = (short)f2bf(e2 * pcol);
    wbuf[(size_t)(b0 + bl + 24) * N + n0 + nl] = (short)f2bf(e3 * pcol);

    // per-row partial sums over this block's 32 n-columns
    float s0 = e0, s1 = e1, s2 = e2, s3 = e3;
#pragma unroll
    for (int off = 16; off > 0; off >>= 1) {
        s0 += __shfl_xor(s0, off);
        s1 += __shfl_xor(s1, off);
        s2 += __shfl_xor(s2, off);
        s3 += __shfl_xor(s3, off);
    }
    if (nl == 0) {
        atomicAdd(rowsum + b0 + bl,      s0);
        atomicAdd(rowsum + b0 + bl + 8,  s1);
        atomicAdd(rowsum + b0 + bl + 16, s2);
        atomicAdd(rowsum + b0 + bl + 24, s3);
    }
}

// ---------------------------------------------------------------------------
extern "C" void kernel_launch(void* const* d_in, const int* in_sizes, int n_in,
                              void* d_out, int out_size, void* d_ws, size_t ws_size,
                              hipStream_t stream) {
    const float* conf     = (const float*)d_in[0]; // [N,D]
    const float* fuse_rep = (const float*)d_in[1]; // [B,FUSE]
    const float* probs    = (const float*)d_in[2]; // [1,N]
    const float* Wq       = (const float*)d_in[3]; // [FUSE,A]
    const float* Wk       = (const float*)d_in[4]; // [D,A]
    const float* wt       = (const float*)d_in[5]; // [A]
    float* out = (float*)d_out;                    // [B,D]

    char* w = (char*)d_ws;
    float* qbuf   = (float*)(w);                    // 512 KB  @ 0
    float* kbuf   = (float*)(w + (1u << 20));       //   1 MB  @ 1M
    short* wbuf   = (short*)(w + (2u << 20));       //   1 MB  @ 2M
    float* rowsum = (float*)(w + (3u << 20));       //   2 KB  @ 3M
    short* fuse_bf= (short*)(w + (4u << 20));       //   1 MB  @ 4M
    short* conf_bf= (short*)(w + (5u << 20));       //   2 MB  @ 5M
    short* confT  = (short*)(w + (7u << 20));       //   2 MB  @ 7M
    short* WqT    = (short*)(w + (9u << 20));       // 512 KB  @ 9M
    short* WkT    = (short*)(w + (9u << 20) + (512u << 10)); // 512 KB

    hipLaunchKernelGGL(cast_kernel, dim3(512), dim3(256), 0, stream,
                       fuse_rep, conf, Wq, Wk, fuse_bf, conf_bf, confT, WqT, WkT,
                       rowsum);
    hipLaunchKernelGGL(qk_gemm_kernel, dim3(192), dim3(256), 0, stream,
                       fuse_bf, conf_bf, WqT, WkT, qbuf, kbuf);
    hipLaunchKernelGGL(scores_kernel, dim3(512), dim3(256), 0, stream,
                       qbuf, kbuf, wt, probs, wbuf, rowsum);
    hipLaunchKernelGGL(fin_gemm_kernel, dim3(D / 64, B / 32), dim3(256), 0, stream,
                       wbuf, confT, rowsum, out);
}